// Round 9
// baseline (393.327 us; speedup 1.0000x reference)
//
#include <hip/hip_runtime.h>
#include <hip/hip_cooperative_groups.h>
#include <hip/hip_bf16.h>
#include <math.h>

namespace cg = cooperative_groups;

#define N_NODES 50000
#define IN_DIM 256
#define OUT_DIM 128
#define NUM_HEADS 2
#define N_EDGES 800000
#define F (OUT_DIM*NUM_HEADS)   /* 256 */
#define LDSP 264                 /* 256 + 8 pad */
#define CSR_NB 256               /* cooperative grid: 1 block/CU guaranteed */
#define CAP 128                  /* per-wave LDS edge chunk in k_agg */

typedef __bf16 bf16;
typedef __bf16 bf16x8 __attribute__((ext_vector_type(8)));
typedef float  f32x4  __attribute__((ext_vector_type(4)));

// ---------------- D1: cooperative CSR builder ----------------------------
// P0 transpose W->Wt + zero deg | P1 hist | P2a local scan | P2b finalize |
// P3 scatter.  256 blocks x 256 threads (tiny resources => co-resident).
__global__ __launch_bounds__(256) void k_csr(const float* __restrict__ W,
                                             const int* __restrict__ src,
                                             const int* __restrict__ dst,
                                             bf16* __restrict__ Wt,
                                             int* __restrict__ deg,
                                             int* __restrict__ incl,
                                             int* __restrict__ bsum,
                                             int* __restrict__ row_start,
                                             int* __restrict__ cursor,
                                             int* __restrict__ sdst) {
    cg::grid_group grid = cg::this_grid();
    __shared__ int lds[256];
    const int nb  = gridDim.x;
    const int t   = threadIdx.x;
    const int b   = blockIdx.x;
    const int gid = b * 256 + t;
    const int gsz = nb * 256;

    // P0: W (256x256 f32) -> Wt (bf16 transposed); zero deg
    for (int i = gid; i < IN_DIM * F; i += gsz) {
        int k = i >> 8, n = i & 255;
        Wt[n * IN_DIM + k] = (bf16)W[i];
    }
    for (int i = gid; i < N_NODES; i += gsz) deg[i] = 0;
    grid.sync();

    // P1: degree histogram
    for (int e = gid; e < N_EDGES; e += gsz) atomicAdd(&deg[src[e]], 1);
    grid.sync();

    // P2a: block-local inclusive scan of its node chunk (chunk=196 <= 256)
    const int chunk = (N_NODES + nb - 1) / nb;
    const int iLoc  = b * chunk + t;
    int v = (t < chunk && iLoc < N_NODES) ? deg[iLoc] : 0;
    lds[t] = v;
    __syncthreads();
    for (int off = 1; off < 256; off <<= 1) {
        int u = (t >= off) ? lds[t - off] : 0;
        __syncthreads();
        lds[t] += u;
        __syncthreads();
    }
    if (t < chunk && iLoc < N_NODES) incl[iLoc] = lds[t];
    if (t == 255) bsum[b] = lds[255];
    grid.sync();

    // P2b: every block scans all nb block-sums, finalizes its chunk
    int bv = (t < nb) ? bsum[t] : 0;
    lds[t] = bv;
    __syncthreads();
    for (int off = 1; off < 256; off <<= 1) {
        int u = (t >= off) ? lds[t - off] : 0;
        __syncthreads();
        lds[t] += u;
        __syncthreads();
    }
    int boff_b = (b > 0) ? lds[b - 1] : 0;
    int total  = lds[nb - 1];
    if (t < chunk && iLoc < N_NODES) {
        int excl = incl[iLoc] - deg[iLoc] + boff_b;
        row_start[iLoc] = excl;
        cursor[iLoc]    = excl;
    }
    if (b == 0 && t == 0) row_start[N_NODES] = total;
    grid.sync();

    // P3: scatter edges into CSR slots (grouped by src)
    for (int e = gid; e < N_EDGES; e += gsz) {
        int s = src[e];
        int pos = atomicAdd(&cursor[s], 1);
        sdst[pos] = dst[e];
    }
}

// ---------------- D2: Wh = x @ W + b, fused s,t  (MFMA bf16) -------------
__global__ __launch_bounds__(256) void k_gemm(const float* __restrict__ X,
                                              const bf16* __restrict__ Wt,
                                              const float* __restrict__ Wb,
                                              const float* __restrict__ Av,
                                              bf16* __restrict__ Wh,
                                              float* __restrict__ s_arr,
                                              float* __restrict__ t_arr) {
    __shared__ bf16 As[64 * LDSP];
    __shared__ float sS[2][64], sT[2][64];
    int t = threadIdx.x;
    int wave = t >> 6, lane = t & 63;
    int quad = lane >> 4, l16 = lane & 15;
    int row0 = blockIdx.x * 64;
    int col0 = wave * 64;
    int h = wave >> 1;

    {
        int rr = t >> 5;
        int cc = (t & 31) * 8;
        #pragma unroll
        for (int i = 0; i < 8; ++i) {
            int r = row0 + 8*i + rr;
            r = (r < N_NODES) ? r : (N_NODES - 1);
            const float* p = X + (size_t)r * IN_DIM + cc;
            f32x4 lo = *(const f32x4*)p;
            f32x4 hi = *(const f32x4*)(p + 4);
            bf16x8 pk;
            #pragma unroll
            for (int q = 0; q < 4; ++q) {
                pk[q]   = (bf16)lo[q];
                pk[q+4] = (bf16)hi[q];
            }
            *(bf16x8*)(As + (8*i + rr) * LDSP + cc) = pk;
        }
    }
    if (t < 128) { sS[t >> 6][t & 63] = 0.f; sT[t >> 6][t & 63] = 0.f; }
    __syncthreads();

    f32x4 acc[4][4] = {};
    #pragma unroll
    for (int ks = 0; ks < 8; ++ks) {
        int kb = ks * 32;
        bf16x8 bfrag[4];
        #pragma unroll
        for (int ni = 0; ni < 4; ++ni)
            bfrag[ni] = *(const bf16x8*)(Wt + (size_t)(col0 + ni*16 + l16)*IN_DIM
                                            + kb + quad*8);
        bf16x8 afrag[4];
        #pragma unroll
        for (int mi = 0; mi < 4; ++mi)
            afrag[mi] = *(const bf16x8*)(As + (mi*16 + l16)*LDSP + kb + quad*8);

        #pragma unroll
        for (int mi = 0; mi < 4; ++mi)
            #pragma unroll
            for (int ni = 0; ni < 4; ++ni)
                acc[mi][ni] = __builtin_amdgcn_mfma_f32_16x16x32_bf16(
                                  afrag[mi], bfrag[ni], acc[mi][ni], 0, 0, 0);
    }

    float bias_l[4], as_l[4], at_l[4];
    #pragma unroll
    for (int ni = 0; ni < 4; ++ni) {
        int c = col0 + ni*16 + l16;
        int d = c & (OUT_DIM - 1);
        bias_l[ni] = Wb[c];
        as_l[ni]   = Av[d];
        at_l[ni]   = Av[OUT_DIM + d];
    }

    #pragma unroll
    for (int mi = 0; mi < 4; ++mi) {
        #pragma unroll
        for (int reg = 0; reg < 4; ++reg) {
            int rl  = mi*16 + quad*4 + reg;
            int row = row0 + rl;
            float ps = 0.f, pt = 0.f;
            #pragma unroll
            for (int ni = 0; ni < 4; ++ni) {
                float val = acc[mi][ni][reg] + bias_l[ni];
                if (row < N_NODES)
                    Wh[(size_t)row*F + col0 + ni*16 + l16] = (bf16)val;
                ps += val * as_l[ni];
                pt += val * at_l[ni];
            }
            #pragma unroll
            for (int m = 8; m >= 1; m >>= 1) {
                ps += __shfl_xor(ps, m);
                pt += __shfl_xor(pt, m);
            }
            if ((lane & 15) == 0) {
                atomicAdd(&sS[h][rl], ps);
                atomicAdd(&sT[h][rl], pt);
            }
        }
    }
    __syncthreads();
    if (t < 128) {
        int hh = t >> 6, rl = t & 63;
        int n = row0 + rl;
        if (n < N_NODES) {
            s_arr[n*2 + hh] = sS[hh][rl];
            t_arr[n*2 + hh] = sT[hh][rl];
        }
    }
}

// ---------------- D3: fused softmax + gather+FMA aggregation -------------
// wave per node. Phase A (per CAP-chunk): lanes over edges compute
// p = exp(leaky(s+t)) (no max shift: softmax is shift-invariant, |e|<~4)
// into wave-local LDS. Phase B: sub=lane>>5 edge-slot, cl=lane&31 col-group,
// gather Wh rows + FMA. All LDS traffic wave-local (in-order DS pipe).
__global__ __launch_bounds__(256) void k_agg(const bf16* __restrict__ Wh,
                                             const float* __restrict__ s_arr,
                                             const float* __restrict__ t_arr,
                                             const int* __restrict__ row_start,
                                             const int* __restrict__ sdst,
                                             float* __restrict__ out) {
    __shared__ float sp0[4][CAP];
    __shared__ float sp1[4][CAP];
    __shared__ int   sd[4][CAP];
    int wave = threadIdx.x >> 6, lane = threadIdx.x & 63;
    int n = blockIdx.x * 4 + wave;
    int sub = lane >> 5, cl = lane & 31;
    int c = cl * 8, h = cl >> 4;
    int beg = row_start[n], end = row_start[n + 1];
    if (beg == end) {       // isolated node: h' = Wh
        if (sub == 0) {
            bf16x8 wh = *(const bf16x8*)(Wh + (size_t)n*F + c);
            f32x4 o0, o1;
            #pragma unroll
            for (int i = 0; i < 4; ++i) { o0[i] = (float)wh[i]; o1[i] = (float)wh[4+i]; }
            *(f32x4*)(out + (size_t)n*F + c)     = o0;
            *(f32x4*)(out + (size_t)n*F + c + 4) = o1;
        }
        return;
    }
    float2 sv = ((const float2*)s_arr)[n];
    float sum0 = 0.f, sum1 = 0.f;
    float a[8] = {0,0,0,0,0,0,0,0};
    float bacc[8] = {0,0,0,0,0,0,0,0};
    const float* sph = h ? sp1[wave] : sp0[wave];

    for (int c0 = beg; c0 < end; c0 += CAP) {
        int cnt = min(CAP, end - c0);
        // Phase A: fill p/d chunk
        for (int j = lane; j < cnt; j += 64) {
            int d = sdst[c0 + j];
            float2 tv = ((const float2*)t_arr)[d];
            float e0 = sv.x + tv.x; e0 = (e0 >= 0.f) ? e0 : 0.2f * e0;
            float e1 = sv.y + tv.y; e1 = (e1 >= 0.f) ? e1 : 0.2f * e1;
            float p0 = __expf(e0), p1 = __expf(e1);
            sp0[wave][j] = p0;
            sp1[wave][j] = p1;
            sd[wave][j]  = d;
            sum0 += p0;
            sum1 += p1;
        }
        // Phase B: gather + FMA (8 edges/iter, 4 per sub-slot)
        int j = 0;
        for (; j + 8 <= cnt; j += 8) {
            int j0 = j + sub, j1 = j + 2 + sub, j2 = j + 4 + sub, j3 = j + 6 + sub;
            int d0 = sd[wave][j0], d1 = sd[wave][j1];
            int d2 = sd[wave][j2], d3 = sd[wave][j3];
            float p0 = sph[j0], p1 = sph[j1], p2 = sph[j2], p3 = sph[j3];
            bf16x8 w0 = *(const bf16x8*)(Wh + (size_t)d0*F + c);
            bf16x8 w1 = *(const bf16x8*)(Wh + (size_t)d1*F + c);
            bf16x8 w2 = *(const bf16x8*)(Wh + (size_t)d2*F + c);
            bf16x8 w3 = *(const bf16x8*)(Wh + (size_t)d3*F + c);
            #pragma unroll
            for (int i = 0; i < 8; ++i) {
                a[i]    += p0 * (float)w0[i];
                bacc[i] += p1 * (float)w1[i];
                a[i]    += p2 * (float)w2[i];
                bacc[i] += p3 * (float)w3[i];
            }
        }
        for (; j < cnt; j += 2) {
            int jj = j + sub;
            int jc = (jj < cnt) ? jj : 0;
            float p = (jj < cnt) ? sph[jc] : 0.f;
            int d = sd[wave][jc];
            bf16x8 w = *(const bf16x8*)(Wh + (size_t)d*F + c);
            #pragma unroll
            for (int i = 0; i < 8; ++i) a[i] += p * (float)w[i];
        }
    }
    // reduce denominators over the full wave
    #pragma unroll
    for (int m = 32; m >= 1; m >>= 1) {
        sum0 += __shfl_xor(sum0, m);
        sum1 += __shfl_xor(sum1, m);
    }
    float inv = 1.f / (h ? sum1 : sum0);
    #pragma unroll
    for (int i = 0; i < 8; ++i) {
        a[i] += bacc[i];
        a[i] += __shfl_xor(a[i], 32);      // merge odd-slot partial
    }
    if (sub == 0) {
        f32x4 o0, o1;
        #pragma unroll
        for (int i = 0; i < 4; ++i) { o0[i] = a[i] * inv; o1[i] = a[4+i] * inv; }
        *(f32x4*)(out + (size_t)n*F + c)     = o0;
        *(f32x4*)(out + (size_t)n*F + c + 4) = o1;
    }
}

// ---------------- launch ----------------
extern "C" void kernel_launch(void* const* d_in, const int* in_sizes, int n_in,
                              void* d_out, int out_size, void* d_ws, size_t ws_size,
                              hipStream_t stream) {
    const float* x  = (const float*)d_in[0];
    const int*   ei = (const int*)d_in[1];
    const float* Ww = (const float*)d_in[2];
    const float* Wb = (const float*)d_in[3];
    const float* a  = (const float*)d_in[4];
    float* out = (float*)d_out;
    const int* src = ei;              // edge_index[0]
    const int* dst = ei + N_EDGES;    // edge_index[1]

    // workspace layout (~30 MB), 16B-aligned slices
    char* ws = (char*)d_ws;
    bf16*  Wh        = (bf16*)ws;   ws += (size_t)N_NODES * F * 2;       // 25.6 MB
    bf16*  Wt        = (bf16*)ws;   ws += (size_t)IN_DIM * F * 2;        // 128 KB
    float* s_arr     = (float*)ws;  ws += (size_t)N_NODES * 2 * 4;
    float* t_arr     = (float*)ws;  ws += (size_t)N_NODES * 2 * 4;
    int*   deg       = (int*)ws;    ws += (size_t)N_NODES * 4;
    int*   incl      = (int*)ws;    ws += (size_t)N_NODES * 4;
    int*   bsum      = (int*)ws;    ws += 256 * 4;
    int*   row_start = (int*)ws;    ws += (size_t)(N_NODES + 1) * 4 + 12; // pad to 16B
    int*   cursor    = (int*)ws;    ws += (size_t)N_NODES * 4;
    int*   sdst      = (int*)ws;    ws += (size_t)N_EDGES * 4;           // 3.2 MB

    // D1: cooperative CSR build (+transpose)
    {
        const float* W_ = Ww;
        const int* src_ = src;
        const int* dst_ = dst;
        bf16* Wt_ = Wt;
        int *deg_ = deg, *incl_ = incl, *bsum_ = bsum;
        int *rs_ = row_start, *cur_ = cursor, *sd_ = sdst;
        void* args[] = { &W_, &src_, &dst_, &Wt_, &deg_, &incl_, &bsum_,
                         &rs_, &cur_, &sd_ };
        hipLaunchCooperativeKernel((const void*)k_csr, dim3(CSR_NB), dim3(256),
                                   args, 0, stream);
    }
    // D2: GEMM + fused s,t
    k_gemm<<<(N_NODES + 63) / 64, 256, 0, stream>>>(x, Wt, Wb, a, Wh, s_arr, t_arr);
    // D3: fused softmax + aggregation
    k_agg<<<N_NODES / 4, 256, 0, stream>>>(Wh, s_arr, t_arr, row_start, sdst, out);
}

// Round 10
// 275.505 us; speedup vs baseline: 1.4277x; 1.4277x over previous
//
#include <hip/hip_runtime.h>
#include <hip/hip_bf16.h>
#include <math.h>

#define N_NODES 50000
#define IN_DIM 256
#define OUT_DIM 128
#define NUM_HEADS 2
#define N_EDGES 800000
#define F (OUT_DIM*NUM_HEADS)   /* 256 */
#define SCAN_B 1024
#define N_SB ((N_NODES + SCAN_B - 1) / SCAN_B)   /* 49 */
#define LDSP 264                 /* 256 + 8 pad */
#define CAP 128                  /* per-wave LDS edge chunk in k_agg */

typedef __bf16 bf16;
typedef __bf16 bf16x8 __attribute__((ext_vector_type(8)));
typedef float  f32x4  __attribute__((ext_vector_type(4)));

// ---------------- K0: W -> Wt (bf16, transposed) + zero deg --------------
__global__ void k_transpose(const float* __restrict__ W, bf16* __restrict__ Wt,
                            int* __restrict__ deg) {
    int k = blockIdx.x;      // 0..IN_DIM-1
    int n = threadIdx.x;     // 0..F-1
    Wt[(size_t)n*IN_DIM + k] = (bf16)W[(size_t)k*F + n];
    int id = blockIdx.x * F + threadIdx.x;
    if (id < N_NODES) deg[id] = 0;
}

// ---------------- K1: Wh = x @ W + b, fused s,t  (MFMA bf16) -------------
__global__ __launch_bounds__(256) void k_gemm(const float* __restrict__ X,
                                              const bf16* __restrict__ Wt,
                                              const float* __restrict__ Wb,
                                              const float* __restrict__ Av,
                                              bf16* __restrict__ Wh,
                                              float* __restrict__ s_arr,
                                              float* __restrict__ t_arr) {
    __shared__ bf16 As[64 * LDSP];
    __shared__ float sS[2][64], sT[2][64];
    int t = threadIdx.x;
    int wave = t >> 6, lane = t & 63;
    int quad = lane >> 4, l16 = lane & 15;
    int row0 = blockIdx.x * 64;
    int col0 = wave * 64;
    int h = wave >> 1;

    {
        int rr = t >> 5;
        int cc = (t & 31) * 8;
        #pragma unroll
        for (int i = 0; i < 8; ++i) {
            int r = row0 + 8*i + rr;
            r = (r < N_NODES) ? r : (N_NODES - 1);
            const float* p = X + (size_t)r * IN_DIM + cc;
            f32x4 lo = *(const f32x4*)p;
            f32x4 hi = *(const f32x4*)(p + 4);
            bf16x8 pk;
            #pragma unroll
            for (int q = 0; q < 4; ++q) {
                pk[q]   = (bf16)lo[q];
                pk[q+4] = (bf16)hi[q];
            }
            *(bf16x8*)(As + (8*i + rr) * LDSP + cc) = pk;
        }
    }
    if (t < 128) { sS[t >> 6][t & 63] = 0.f; sT[t >> 6][t & 63] = 0.f; }
    __syncthreads();

    f32x4 acc[4][4] = {};
    #pragma unroll
    for (int ks = 0; ks < 8; ++ks) {
        int kb = ks * 32;
        bf16x8 bfrag[4];
        #pragma unroll
        for (int ni = 0; ni < 4; ++ni)
            bfrag[ni] = *(const bf16x8*)(Wt + (size_t)(col0 + ni*16 + l16)*IN_DIM
                                            + kb + quad*8);
        bf16x8 afrag[4];
        #pragma unroll
        for (int mi = 0; mi < 4; ++mi)
            afrag[mi] = *(const bf16x8*)(As + (mi*16 + l16)*LDSP + kb + quad*8);

        #pragma unroll
        for (int mi = 0; mi < 4; ++mi)
            #pragma unroll
            for (int ni = 0; ni < 4; ++ni)
                acc[mi][ni] = __builtin_amdgcn_mfma_f32_16x16x32_bf16(
                                  afrag[mi], bfrag[ni], acc[mi][ni], 0, 0, 0);
    }

    float bias_l[4], as_l[4], at_l[4];
    #pragma unroll
    for (int ni = 0; ni < 4; ++ni) {
        int c = col0 + ni*16 + l16;
        int d = c & (OUT_DIM - 1);
        bias_l[ni] = Wb[c];
        as_l[ni]   = Av[d];
        at_l[ni]   = Av[OUT_DIM + d];
    }

    #pragma unroll
    for (int mi = 0; mi < 4; ++mi) {
        #pragma unroll
        for (int reg = 0; reg < 4; ++reg) {
            int rl  = mi*16 + quad*4 + reg;
            int row = row0 + rl;
            float ps = 0.f, pt = 0.f;
            #pragma unroll
            for (int ni = 0; ni < 4; ++ni) {
                float val = acc[mi][ni][reg] + bias_l[ni];
                if (row < N_NODES)
                    Wh[(size_t)row*F + col0 + ni*16 + l16] = (bf16)val;
                ps += val * as_l[ni];
                pt += val * at_l[ni];
            }
            #pragma unroll
            for (int m = 8; m >= 1; m >>= 1) {
                ps += __shfl_xor(ps, m);
                pt += __shfl_xor(pt, m);
            }
            if ((lane & 15) == 0) {
                atomicAdd(&sS[h][rl], ps);
                atomicAdd(&sT[h][rl], pt);
            }
        }
    }
    __syncthreads();
    if (t < 128) {
        int hh = t >> 6, rl = t & 63;
        int n = row0 + rl;
        if (n < N_NODES) {
            s_arr[n*2 + hh] = sS[hh][rl];
            t_arr[n*2 + hh] = sT[hh][rl];
        }
    }
}

// ---------------- K3: degree histogram over src ----------------
__global__ void k_hist(const int* __restrict__ src, int* __restrict__ deg) {
    int e = blockIdx.x * 256 + threadIdx.x;
    if (e < N_EDGES) atomicAdd(&deg[src[e]], 1);
}

// ---------------- K4a: per-block inclusive scan ----------------
__global__ __launch_bounds__(SCAN_B) void k_scan_local(const int* __restrict__ deg,
                                                       int* __restrict__ incl,
                                                       int* __restrict__ bsum) {
    __shared__ int lds[SCAN_B];
    int t = threadIdx.x;
    int i = blockIdx.x * SCAN_B + t;
    int v = (i < N_NODES) ? deg[i] : 0;
    lds[t] = v;
    __syncthreads();
    for (int off = 1; off < SCAN_B; off <<= 1) {
        int u = (t >= off) ? lds[t - off] : 0;
        __syncthreads();
        lds[t] += u;
        __syncthreads();
    }
    if (i < N_NODES) incl[i] = lds[t];
    if (t == SCAN_B - 1) bsum[blockIdx.x] = lds[t];
}

// ---------------- K4b: finalize exclusive scan (folds block-sum scan) ----
__global__ __launch_bounds__(256) void k_scan_final(const int* __restrict__ incl,
                                                    const int* __restrict__ deg,
                                                    const int* __restrict__ bsum,
                                                    int* __restrict__ row_start,
                                                    int* __restrict__ cursor) {
    __shared__ int sboff[64];
    int t = threadIdx.x;
    if (t < 64) {
        int orig = (t < N_SB) ? bsum[t] : 0;
        int v = orig;
        #pragma unroll
        for (int off = 1; off < 64; off <<= 1) {
            int u = __shfl_up(v, off);
            if (t >= off) v += u;
        }
        sboff[t] = v - orig;
        if (t == 63 && blockIdx.x == 0) row_start[N_NODES] = v;
    }
    __syncthreads();
    int i = blockIdx.x * 256 + t;
    if (i < N_NODES) {
        int excl = incl[i] - deg[i] + sboff[i >> 10];
        row_start[i] = excl;
        cursor[i]    = excl;
    }
}

// ---------------- K5: scatter edges into CSR slots (grouped by src) ------
__global__ void k_scatter(const int* __restrict__ src, const int* __restrict__ dst,
                          int* __restrict__ cursor, int* __restrict__ sorted_dst) {
    int e = blockIdx.x * 256 + threadIdx.x;
    if (e < N_EDGES) {
        int s = src[e];
        int pos = atomicAdd(&cursor[s], 1);
        sorted_dst[pos] = dst[e];
    }
}

// ---------------- K6: fused softmax + gather+FMA aggregation -------------
// wave per node. Phase A (per CAP-chunk): lanes over edges compute
// p = exp(leaky(s+t)) (no max shift: softmax shift-invariant, |e| small)
// into wave-local LDS. Phase B: sub=lane>>5 edge-slot, cl=lane&31 col-group,
// gather Wh rows (16B/lane) + FMA, 8 edges/iter.
__global__ __launch_bounds__(256) void k_agg(const bf16* __restrict__ Wh,
                                             const float* __restrict__ s_arr,
                                             const float* __restrict__ t_arr,
                                             const int* __restrict__ row_start,
                                             const int* __restrict__ sdst,
                                             float* __restrict__ out) {
    __shared__ float sp0[4][CAP];
    __shared__ float sp1[4][CAP];
    __shared__ int   sd[4][CAP];
    int wave = threadIdx.x >> 6, lane = threadIdx.x & 63;
    int n = blockIdx.x * 4 + wave;
    int sub = lane >> 5, cl = lane & 31;
    int c = cl * 8, h = cl >> 4;
    int beg = row_start[n], end = row_start[n + 1];
    if (beg == end) {       // isolated node: h' = Wh
        if (sub == 0) {
            bf16x8 wh = *(const bf16x8*)(Wh + (size_t)n*F + c);
            f32x4 o0, o1;
            #pragma unroll
            for (int i = 0; i < 4; ++i) { o0[i] = (float)wh[i]; o1[i] = (float)wh[4+i]; }
            *(f32x4*)(out + (size_t)n*F + c)     = o0;
            *(f32x4*)(out + (size_t)n*F + c + 4) = o1;
        }
        return;
    }
    float2 sv = ((const float2*)s_arr)[n];
    float sum0 = 0.f, sum1 = 0.f;
    float a[8] = {0,0,0,0,0,0,0,0};
    float bacc[8] = {0,0,0,0,0,0,0,0};
    const float* sph = h ? sp1[wave] : sp0[wave];

    for (int c0 = beg; c0 < end; c0 += CAP) {
        int cnt = min(CAP, end - c0);
        // Phase A: fill p/d chunk (wave-local, no barrier needed beyond DS order)
        for (int j = lane; j < cnt; j += 64) {
            int d = sdst[c0 + j];
            float2 tv = ((const float2*)t_arr)[d];
            float e0 = sv.x + tv.x; e0 = (e0 >= 0.f) ? e0 : 0.2f * e0;
            float e1 = sv.y + tv.y; e1 = (e1 >= 0.f) ? e1 : 0.2f * e1;
            float p0 = __expf(e0), p1 = __expf(e1);
            sp0[wave][j] = p0;
            sp1[wave][j] = p1;
            sd[wave][j]  = d;
            sum0 += p0;
            sum1 += p1;
        }
        // Phase B: gather + FMA (8 edges/iter, 4 per sub-slot)
        int j = 0;
        for (; j + 8 <= cnt; j += 8) {
            int j0 = j + sub, j1 = j + 2 + sub, j2 = j + 4 + sub, j3 = j + 6 + sub;
            int d0 = sd[wave][j0], d1 = sd[wave][j1];
            int d2 = sd[wave][j2], d3 = sd[wave][j3];
            float p0 = sph[j0], p1 = sph[j1], p2 = sph[j2], p3 = sph[j3];
            bf16x8 w0 = *(const bf16x8*)(Wh + (size_t)d0*F + c);
            bf16x8 w1 = *(const bf16x8*)(Wh + (size_t)d1*F + c);
            bf16x8 w2 = *(const bf16x8*)(Wh + (size_t)d2*F + c);
            bf16x8 w3 = *(const bf16x8*)(Wh + (size_t)d3*F + c);
            #pragma unroll
            for (int i = 0; i < 8; ++i) {
                a[i]    += p0 * (float)w0[i];
                bacc[i] += p1 * (float)w1[i];
                a[i]    += p2 * (float)w2[i];
                bacc[i] += p3 * (float)w3[i];
            }
        }
        for (; j < cnt; j += 2) {
            int jj = j + sub;
            int jc = (jj < cnt) ? jj : 0;
            float p = (jj < cnt) ? sph[jc] : 0.f;
            int d = sd[wave][jc];
            bf16x8 w = *(const bf16x8*)(Wh + (size_t)d*F + c);
            #pragma unroll
            for (int i = 0; i < 8; ++i) a[i] += p * (float)w[i];
        }
    }
    #pragma unroll
    for (int m = 32; m >= 1; m >>= 1) {
        sum0 += __shfl_xor(sum0, m);
        sum1 += __shfl_xor(sum1, m);
    }
    float inv = 1.f / (h ? sum1 : sum0);
    #pragma unroll
    for (int i = 0; i < 8; ++i) {
        a[i] += bacc[i];
        a[i] += __shfl_xor(a[i], 32);      // merge odd-slot partial
    }
    if (sub == 0) {
        f32x4 o0, o1;
        #pragma unroll
        for (int i = 0; i < 4; ++i) { o0[i] = a[i] * inv; o1[i] = a[4+i] * inv; }
        *(f32x4*)(out + (size_t)n*F + c)     = o0;
        *(f32x4*)(out + (size_t)n*F + c + 4) = o1;
    }
}

// ---------------- launch ----------------
extern "C" void kernel_launch(void* const* d_in, const int* in_sizes, int n_in,
                              void* d_out, int out_size, void* d_ws, size_t ws_size,
                              hipStream_t stream) {
    const float* x  = (const float*)d_in[0];
    const int*   ei = (const int*)d_in[1];
    const float* Ww = (const float*)d_in[2];
    const float* Wb = (const float*)d_in[3];
    const float* a  = (const float*)d_in[4];
    float* out = (float*)d_out;
    const int* src = ei;              // edge_index[0]
    const int* dst = ei + N_EDGES;    // edge_index[1]

    // workspace layout (~30 MB), 16B-aligned slices
    char* ws = (char*)d_ws;
    bf16*  Wh        = (bf16*)ws;   ws += (size_t)N_NODES * F * 2;       // 25.6 MB
    bf16*  Wt        = (bf16*)ws;   ws += (size_t)IN_DIM * F * 2;        // 128 KB
    float* s_arr     = (float*)ws;  ws += (size_t)N_NODES * 2 * 4;
    float* t_arr     = (float*)ws;  ws += (size_t)N_NODES * 2 * 4;
    int*   deg       = (int*)ws;    ws += (size_t)N_NODES * 4;
    int*   incl      = (int*)ws;    ws += (size_t)N_NODES * 4;
    int*   bsum      = (int*)ws;    ws += 64 * 4;
    int*   row_start = (int*)ws;    ws += (size_t)(N_NODES + 1) * 4 + 12; // pad to 16B
    int*   cursor    = (int*)ws;    ws += (size_t)N_NODES * 4;
    int*   sdst      = (int*)ws;    ws += (size_t)N_EDGES * 4;           // 3.2 MB

    k_transpose<<<IN_DIM, F, 0, stream>>>(Ww, Wt, deg);
    k_gemm<<<(N_NODES + 63) / 64, 256, 0, stream>>>(x, Wt, Wb, a, Wh, s_arr, t_arr);
    k_hist<<<(N_EDGES + 255) / 256, 256, 0, stream>>>(src, deg);
    k_scan_local<<<N_SB, SCAN_B, 0, stream>>>(deg, incl, bsum);
    k_scan_final<<<(N_NODES + 255) / 256, 256, 0, stream>>>(incl, deg, bsum, row_start, cursor);
    k_scatter<<<(N_EDGES + 255) / 256, 256, 0, stream>>>(src, dst, cursor, sdst);
    k_agg<<<N_NODES / 4, 256, 0, stream>>>(Wh, s_arr, t_arr, row_start, sdst, out);
}

// Round 11
// 272.881 us; speedup vs baseline: 1.4414x; 1.0096x over previous
//
#include <hip/hip_runtime.h>
#include <hip/hip_bf16.h>
#include <math.h>

#define N_NODES 50000
#define IN_DIM 256
#define OUT_DIM 128
#define NUM_HEADS 2
#define N_EDGES 800000
#define F (OUT_DIM*NUM_HEADS)   /* 256 */
#define SCAN_B 1024
#define N_SB ((N_NODES + SCAN_B - 1) / SCAN_B)   /* 49 */
#define LDSP 264                 /* 256 + 8 pad: 132-word row stride = 4 mod 32 banks */
#define CAP 128                  /* per-wave LDS edge chunk in k_agg */

typedef __bf16 bf16;
typedef __bf16 bf16x8 __attribute__((ext_vector_type(8)));
typedef float  f32x4  __attribute__((ext_vector_type(4)));

// ---------------- K0: W -> Wt (bf16, transposed) + zero deg --------------
__global__ void k_transpose(const float* __restrict__ W, bf16* __restrict__ Wt,
                            int* __restrict__ deg) {
    int k = blockIdx.x;      // 0..IN_DIM-1
    int n = threadIdx.x;     // 0..F-1
    Wt[(size_t)n*IN_DIM + k] = (bf16)W[(size_t)k*F + n];
    int id = blockIdx.x * F + threadIdx.x;
    if (id < N_NODES) deg[id] = 0;
}

// ---------------- K1: Wh = x @ W + b, fused s,t + hist  (MFMA bf16) ------
// Block: 64 rows x 256 cols, 4 waves. Full-K LDS A-tile, one staging barrier.
// Also: grid-stride degree histogram (deg zeroed by k_transpose dispatch).
// Epilogue: s,t via shuffle+LDS atomics; Wh stored via LDS repack so each
// wave issues 8 coalesced dwordx4 stores instead of 64 scattered 2B stores.
__global__ __launch_bounds__(256) void k_gemm(const float* __restrict__ X,
                                              const bf16* __restrict__ Wt,
                                              const float* __restrict__ Wb,
                                              const float* __restrict__ Av,
                                              const int* __restrict__ src,
                                              int* __restrict__ deg,
                                              bf16* __restrict__ Wh,
                                              float* __restrict__ s_arr,
                                              float* __restrict__ t_arr) {
    __shared__ bf16 As[64 * LDSP];
    __shared__ float sS[2][64], sT[2][64];
    int t = threadIdx.x;
    int wave = t >> 6, lane = t & 63;
    int quad = lane >> 4, l16 = lane & 15;
    int row0 = blockIdx.x * 64;
    int col0 = wave * 64;
    int h = wave >> 1;

    // fused degree histogram (overlaps with staging latency)
    {
        int gid = blockIdx.x * 256 + t;
        int gsz = gridDim.x * 256;
        for (int e = gid; e < N_EDGES; e += gsz)
            atomicAdd(&deg[src[e]], 1);
    }

    // staging: thread t, chunk i: row = 8i + (t>>5), cols (t&31)*8..+8
    {
        int rr = t >> 5;
        int cc = (t & 31) * 8;
        #pragma unroll
        for (int i = 0; i < 8; ++i) {
            int r = row0 + 8*i + rr;
            r = (r < N_NODES) ? r : (N_NODES - 1);
            const float* p = X + (size_t)r * IN_DIM + cc;
            f32x4 lo = *(const f32x4*)p;
            f32x4 hi = *(const f32x4*)(p + 4);
            bf16x8 pk;
            #pragma unroll
            for (int q = 0; q < 4; ++q) {
                pk[q]   = (bf16)lo[q];
                pk[q+4] = (bf16)hi[q];
            }
            *(bf16x8*)(As + (8*i + rr) * LDSP + cc) = pk;
        }
    }
    if (t < 128) { sS[t >> 6][t & 63] = 0.f; sT[t >> 6][t & 63] = 0.f; }
    __syncthreads();

    f32x4 acc[4][4] = {};
    #pragma unroll
    for (int ks = 0; ks < 8; ++ks) {
        int kb = ks * 32;
        bf16x8 bfrag[4];
        #pragma unroll
        for (int ni = 0; ni < 4; ++ni)
            bfrag[ni] = *(const bf16x8*)(Wt + (size_t)(col0 + ni*16 + l16)*IN_DIM
                                            + kb + quad*8);
        bf16x8 afrag[4];
        #pragma unroll
        for (int mi = 0; mi < 4; ++mi)
            afrag[mi] = *(const bf16x8*)(As + (mi*16 + l16)*LDSP + kb + quad*8);

        #pragma unroll
        for (int mi = 0; mi < 4; ++mi)
            #pragma unroll
            for (int ni = 0; ni < 4; ++ni)
                acc[mi][ni] = __builtin_amdgcn_mfma_f32_16x16x32_bf16(
                                  afrag[mi], bfrag[ni], acc[mi][ni], 0, 0, 0);
    }

    float bias_l[4], as_l[4], at_l[4];
    #pragma unroll
    for (int ni = 0; ni < 4; ++ni) {
        int c = col0 + ni*16 + l16;
        int d = c & (OUT_DIM - 1);
        bias_l[ni] = Wb[c];
        as_l[ni]   = Av[d];
        at_l[ni]   = Av[OUT_DIM + d];
    }

    // s,t partials from accumulators (C layout: col=lane&15, row=quad*4+reg)
    #pragma unroll
    for (int mi = 0; mi < 4; ++mi) {
        #pragma unroll
        for (int reg = 0; reg < 4; ++reg) {
            int rl = mi*16 + quad*4 + reg;
            float ps = 0.f, pt = 0.f;
            #pragma unroll
            for (int ni = 0; ni < 4; ++ni) {
                float val = acc[mi][ni][reg] + bias_l[ni];
                ps += val * as_l[ni];
                pt += val * at_l[ni];
            }
            #pragma unroll
            for (int m = 8; m >= 1; m >>= 1) {
                ps += __shfl_xor(ps, m);
                pt += __shfl_xor(pt, m);
            }
            if ((lane & 15) == 0) {
                atomicAdd(&sS[h][rl], ps);
                atomicAdd(&sT[h][rl], pt);
            }
        }
    }

    // repack acc -> As (bias added) for coalesced Wh stores
    __syncthreads();          // all waves done with As compute reads
    #pragma unroll
    for (int mi = 0; mi < 4; ++mi)
        #pragma unroll
        for (int ni = 0; ni < 4; ++ni) {
            int cc = col0 + ni*16 + l16;
            #pragma unroll
            for (int reg = 0; reg < 4; ++reg) {
                int rl = mi*16 + quad*4 + reg;
                As[rl*LDSP + cc] = (bf16)(acc[mi][ni][reg] + bias_l[ni]);
            }
        }
    __syncthreads();

    // coalesced write-out: 8 rounds x (ds_read_b128 + global_store_dwordx4)
    #pragma unroll
    for (int i = 0; i < 8; ++i) {
        int idx = i * 2048 + t * 8;     // 2048 elems (=8 rows) per round
        int row = idx >> 8;
        int cc  = idx & 255;
        bf16x8 v = *(const bf16x8*)(As + row*LDSP + cc);
        int grow = row0 + row;
        if (grow < N_NODES)
            *(bf16x8*)(Wh + (size_t)grow*F + cc) = v;
    }

    if (t < 128) {
        int hh = t >> 6, rl = t & 63;
        int n = row0 + rl;
        if (n < N_NODES) {
            s_arr[n*2 + hh] = sS[hh][rl];
            t_arr[n*2 + hh] = sT[hh][rl];
        }
    }
}

// ---------------- K4a: per-block inclusive scan ----------------
__global__ __launch_bounds__(SCAN_B) void k_scan_local(const int* __restrict__ deg,
                                                       int* __restrict__ incl,
                                                       int* __restrict__ bsum) {
    __shared__ int lds[SCAN_B];
    int t = threadIdx.x;
    int i = blockIdx.x * SCAN_B + t;
    int v = (i < N_NODES) ? deg[i] : 0;
    lds[t] = v;
    __syncthreads();
    for (int off = 1; off < SCAN_B; off <<= 1) {
        int u = (t >= off) ? lds[t - off] : 0;
        __syncthreads();
        lds[t] += u;
        __syncthreads();
    }
    if (i < N_NODES) incl[i] = lds[t];
    if (t == SCAN_B - 1) bsum[blockIdx.x] = lds[t];
}

// ---------------- K4b: finalize exclusive scan (folds block-sum scan) ----
__global__ __launch_bounds__(256) void k_scan_final(const int* __restrict__ incl,
                                                    const int* __restrict__ deg,
                                                    const int* __restrict__ bsum,
                                                    int* __restrict__ row_start,
                                                    int* __restrict__ cursor) {
    __shared__ int sboff[64];
    int t = threadIdx.x;
    if (t < 64) {
        int orig = (t < N_SB) ? bsum[t] : 0;
        int v = orig;
        #pragma unroll
        for (int off = 1; off < 64; off <<= 1) {
            int u = __shfl_up(v, off);
            if (t >= off) v += u;
        }
        sboff[t] = v - orig;
        if (t == 63 && blockIdx.x == 0) row_start[N_NODES] = v;
    }
    __syncthreads();
    int i = blockIdx.x * 256 + t;
    if (i < N_NODES) {
        int excl = incl[i] - deg[i] + sboff[i >> 10];
        row_start[i] = excl;
        cursor[i]    = excl;
    }
}

// ---------------- K5: scatter edges into CSR slots (grouped by src) ------
__global__ void k_scatter(const int* __restrict__ src, const int* __restrict__ dst,
                          int* __restrict__ cursor, int* __restrict__ sorted_dst) {
    int e = blockIdx.x * 256 + threadIdx.x;
    if (e < N_EDGES) {
        int s = src[e];
        int pos = atomicAdd(&cursor[s], 1);
        sorted_dst[pos] = dst[e];
    }
}

// ---------------- K6: fused softmax + gather+FMA aggregation -------------
// wave per node. Phase A (per CAP-chunk): lanes over edges compute
// p = exp(leaky(s+t)) (no max shift: softmax shift-invariant, |e| small)
// into wave-local LDS. Phase B: sub=lane>>5 edge-slot, cl=lane&31 col-group,
// gather Wh rows (16B/lane) + FMA, 8 edges/iter.
__global__ __launch_bounds__(256) void k_agg(const bf16* __restrict__ Wh,
                                             const float* __restrict__ s_arr,
                                             const float* __restrict__ t_arr,
                                             const int* __restrict__ row_start,
                                             const int* __restrict__ sdst,
                                             float* __restrict__ out) {
    __shared__ float sp0[4][CAP];
    __shared__ float sp1[4][CAP];
    __shared__ int   sd[4][CAP];
    int wave = threadIdx.x >> 6, lane = threadIdx.x & 63;
    int n = blockIdx.x * 4 + wave;
    int sub = lane >> 5, cl = lane & 31;
    int c = cl * 8, h = cl >> 4;
    int beg = row_start[n], end = row_start[n + 1];
    if (beg == end) {       // isolated node: h' = Wh
        if (sub == 0) {
            bf16x8 wh = *(const bf16x8*)(Wh + (size_t)n*F + c);
            f32x4 o0, o1;
            #pragma unroll
            for (int i = 0; i < 4; ++i) { o0[i] = (float)wh[i]; o1[i] = (float)wh[4+i]; }
            *(f32x4*)(out + (size_t)n*F + c)     = o0;
            *(f32x4*)(out + (size_t)n*F + c + 4) = o1;
        }
        return;
    }
    float2 sv = ((const float2*)s_arr)[n];
    float sum0 = 0.f, sum1 = 0.f;
    float a[8] = {0,0,0,0,0,0,0,0};
    float bacc[8] = {0,0,0,0,0,0,0,0};
    const float* sph = h ? sp1[wave] : sp0[wave];

    for (int c0 = beg; c0 < end; c0 += CAP) {
        int cnt = min(CAP, end - c0);
        // Phase A: fill p/d chunk (wave-local)
        for (int j = lane; j < cnt; j += 64) {
            int d = sdst[c0 + j];
            float2 tv = ((const float2*)t_arr)[d];
            float e0 = sv.x + tv.x; e0 = (e0 >= 0.f) ? e0 : 0.2f * e0;
            float e1 = sv.y + tv.y; e1 = (e1 >= 0.f) ? e1 : 0.2f * e1;
            float p0 = __expf(e0), p1 = __expf(e1);
            sp0[wave][j] = p0;
            sp1[wave][j] = p1;
            sd[wave][j]  = d;
            sum0 += p0;
            sum1 += p1;
        }
        // Phase B: gather + FMA (8 edges/iter, 4 per sub-slot)
        int j = 0;
        for (; j + 8 <= cnt; j += 8) {
            int j0 = j + sub, j1 = j + 2 + sub, j2 = j + 4 + sub, j3 = j + 6 + sub;
            int d0 = sd[wave][j0], d1 = sd[wave][j1];
            int d2 = sd[wave][j2], d3 = sd[wave][j3];
            float p0 = sph[j0], p1 = sph[j1], p2 = sph[j2], p3 = sph[j3];
            bf16x8 w0 = *(const bf16x8*)(Wh + (size_t)d0*F + c);
            bf16x8 w1 = *(const bf16x8*)(Wh + (size_t)d1*F + c);
            bf16x8 w2 = *(const bf16x8*)(Wh + (size_t)d2*F + c);
            bf16x8 w3 = *(const bf16x8*)(Wh + (size_t)d3*F + c);
            #pragma unroll
            for (int i = 0; i < 8; ++i) {
                a[i]    += p0 * (float)w0[i];
                bacc[i] += p1 * (float)w1[i];
                a[i]    += p2 * (float)w2[i];
                bacc[i] += p3 * (float)w3[i];
            }
        }
        for (; j < cnt; j += 2) {
            int jj = j + sub;
            int jc = (jj < cnt) ? jj : 0;
            float p = (jj < cnt) ? sph[jc] : 0.f;
            int d = sd[wave][jc];
            bf16x8 w = *(const bf16x8*)(Wh + (size_t)d*F + c);
            #pragma unroll
            for (int i = 0; i < 8; ++i) a[i] += p * (float)w[i];
        }
    }
    #pragma unroll
    for (int m = 32; m >= 1; m >>= 1) {
        sum0 += __shfl_xor(sum0, m);
        sum1 += __shfl_xor(sum1, m);
    }
    float inv = 1.f / (h ? sum1 : sum0);
    #pragma unroll
    for (int i = 0; i < 8; ++i) {
        a[i] += bacc[i];
        a[i] += __shfl_xor(a[i], 32);      // merge odd-slot partial
    }
    if (sub == 0) {
        f32x4 o0, o1;
        #pragma unroll
        for (int i = 0; i < 4; ++i) { o0[i] = a[i] * inv; o1[i] = a[4+i] * inv; }
        *(f32x4*)(out + (size_t)n*F + c)     = o0;
        *(f32x4*)(out + (size_t)n*F + c + 4) = o1;
    }
}

// ---------------- launch ----------------
extern "C" void kernel_launch(void* const* d_in, const int* in_sizes, int n_in,
                              void* d_out, int out_size, void* d_ws, size_t ws_size,
                              hipStream_t stream) {
    const float* x  = (const float*)d_in[0];
    const int*   ei = (const int*)d_in[1];
    const float* Ww = (const float*)d_in[2];
    const float* Wb = (const float*)d_in[3];
    const float* a  = (const float*)d_in[4];
    float* out = (float*)d_out;
    const int* src = ei;              // edge_index[0]
    const int* dst = ei + N_EDGES;    // edge_index[1]

    // workspace layout (~30 MB), 16B-aligned slices
    char* ws = (char*)d_ws;
    bf16*  Wh        = (bf16*)ws;   ws += (size_t)N_NODES * F * 2;       // 25.6 MB
    bf16*  Wt        = (bf16*)ws;   ws += (size_t)IN_DIM * F * 2;        // 128 KB
    float* s_arr     = (float*)ws;  ws += (size_t)N_NODES * 2 * 4;
    float* t_arr     = (float*)ws;  ws += (size_t)N_NODES * 2 * 4;
    int*   deg       = (int*)ws;    ws += (size_t)N_NODES * 4;
    int*   incl      = (int*)ws;    ws += (size_t)N_NODES * 4;
    int*   bsum      = (int*)ws;    ws += 64 * 4;
    int*   row_start = (int*)ws;    ws += (size_t)(N_NODES + 1) * 4 + 12; // pad to 16B
    int*   cursor    = (int*)ws;    ws += (size_t)N_NODES * 4;
    int*   sdst      = (int*)ws;    ws += (size_t)N_EDGES * 4;           // 3.2 MB

    k_transpose<<<IN_DIM, F, 0, stream>>>(Ww, Wt, deg);
    k_gemm<<<(N_NODES + 63) / 64, 256, 0, stream>>>(x, Wt, Wb, a, src, deg,
                                                    Wh, s_arr, t_arr);
    k_scan_local<<<N_SB, SCAN_B, 0, stream>>>(deg, incl, bsum);
    k_scan_final<<<(N_NODES + 255) / 256, 256, 0, stream>>>(incl, deg, bsum, row_start, cursor);
    k_scatter<<<(N_EDGES + 255) / 256, 256, 0, stream>>>(src, dst, cursor, sdst);
    k_agg<<<N_NODES / 4, 256, 0, stream>>>(Wh, s_arr, t_arr, row_start, sdst, out);
}